// Round 4
// baseline (2755.868 us; speedup 1.0000x reference)
//
#include <hip/hip_runtime.h>
#include <hip/hip_bf16.h>
#include <math.h>

#define S_  1024
#define E_  2560
#define H_  32
#define D_  80
#define E3_ 7680
#define M_  2048   // B*S
#define QK_ 5120   // packed Q|K row width in ws

static __device__ __forceinline__ float bf2f(unsigned short u) {
    unsigned int i = ((unsigned int)u) << 16;
    float f; __builtin_memcpy(&f, &i, 4); return f;
}
static __device__ __forceinline__ unsigned short f2bf(float f) {
    unsigned int i; __builtin_memcpy(&i, &f, 4);
    i += 0x7fffu + ((i >> 16) & 1u);
    return (unsigned short)(i >> 16);
}
static __device__ __forceinline__ void unpack8(uint4 v, float* f) {
    unsigned int u[4] = {v.x, v.y, v.z, v.w};
#pragma unroll
    for (int q = 0; q < 4; ++q) {
        unsigned int lo = u[q] << 16;
        unsigned int hi = u[q] & 0xffff0000u;
        __builtin_memcpy(&f[2*q],   &lo, 4);
        __builtin_memcpy(&f[2*q+1], &hi, 4);
    }
}

union U8 { uint4 v; unsigned short s[8]; };

// load 8 consecutive elements as bf16, from bf16 or fp32 source
static __device__ __forceinline__ U8 ld8(const void* base, size_t off, bool f32) {
    U8 r;
    if (f32) {
        const float* p = (const float*)base + off;
        float4 a = *(const float4*)p;
        float4 b = *(const float4*)(p + 4);
        r.s[0]=f2bf(a.x); r.s[1]=f2bf(a.y); r.s[2]=f2bf(a.z); r.s[3]=f2bf(a.w);
        r.s[4]=f2bf(b.x); r.s[5]=f2bf(b.y); r.s[6]=f2bf(b.z); r.s[7]=f2bf(b.w);
    } else {
        r.v = *(const uint4*)((const unsigned short*)base + off);
    }
    return r;
}
static __device__ __forceinline__ float lds1(const void* base, int i, bool f32) {
    return f32 ? ((const float*)base)[i] : bf2f(((const unsigned short*)base)[i]);
}
static __device__ __forceinline__ float4 ld_bf4(const unsigned short* p) {
    ushort4 u = *(const ushort4*)p;   // 8B-aligned
    return make_float4(bf2f(u.x), bf2f(u.y), bf2f(u.z), bf2f(u.w));
}

// dtype probe: bf16 weights (*0.02) never have exponent >= 132 (|x|>=32);
// fp32 misread as ushort pairs has ~48% of low halves with exp >= 132.
__global__ void detect_kernel(const unsigned short* __restrict__ w, int* __restrict__ flag) {
    __shared__ int total;
    const int t = threadIdx.x;
    if (t == 0) total = 0;
    __syncthreads();
    int cnt = 0;
#pragma unroll
    for (int i = 0; i < 16; ++i) {
        unsigned short u = w[t * 16 + i];
        int e = (u >> 7) & 0xFF;
        if (e >= 132) cnt++;
    }
    atomicAdd(&total, cnt);
    __syncthreads();
    if (t == 0) *flag = (total > 8) ? 1 : 0;
}

// C[M,N] = A[M,K] @ W[K,N] + bias[N]; internal compute bf16->fp32.
// A_BF16: A is an internal bf16 buffer (ignore flag for A). Otherwise A dtype per flag.
// W/bias dtype always per flag (they are harness inputs).
// Columns [0,ncut) -> dst0 (row stride sd0), [ncut,N) -> dst1 (stride sd1).
// MATCH_OUT: store fp32 when flag says fp32 world (for d_out); else always bf16.
template <bool A_BF16, bool MATCH_OUT>
__global__ __launch_bounds__(256, 3) void gemm_bias_kernel(
    const void* __restrict__ A, int lda,
    const void* __restrict__ W, int N, int K,
    const void* __restrict__ bias,
    void* __restrict__ dst0, int sd0,
    void* __restrict__ dst1, int sd1, int ncut,
    const int* __restrict__ flag)
{
    __shared__ unsigned short As[32 * 136];  // [k][m]
    __shared__ unsigned short Ws[32 * 136];  // [k][n]

    const bool f32  = (*flag != 0);
    const bool af32 = A_BF16 ? false : f32;

    const int t  = threadIdx.x;
    const int tx = t & 15;          // n dir
    const int ty = t >> 4;          // m dir
    const int m0 = blockIdx.y * 128;
    const int n0 = blockIdx.x * 128;

    const int ar = t >> 2;          // A-staging row (and +64)
    const int kk = (t & 3) * 8;     // A-staging k group
    const int wk = t >> 3;          // W-staging k row
    const int wn = (t & 7) * 16;    // W-staging n group

    float acc[8][8];
#pragma unroll
    for (int i = 0; i < 8; ++i)
#pragma unroll
        for (int j = 0; j < 8; ++j) acc[i][j] = 0.f;

    for (int k0 = 0; k0 < K; k0 += 32) {
        U8 a0u = ld8(A, (size_t)(m0 + ar) * lda + k0 + kk, af32);
        U8 a1u = ld8(A, (size_t)(m0 + ar + 64) * lda + k0 + kk, af32);
        U8 w0  = ld8(W, (size_t)(k0 + wk) * N + n0 + wn, f32);
        U8 w1  = ld8(W, (size_t)(k0 + wk) * N + n0 + wn + 8, f32);
        __syncthreads();  // prev tile's LDS reads complete
#pragma unroll
        for (int j = 0; j < 8; ++j) {
            As[(kk + j) * 136 + ar]      = a0u.s[j];
            As[(kk + j) * 136 + ar + 64] = a1u.s[j];
        }
        *(uint4*)&Ws[wk * 136 + wn]     = w0.v;
        *(uint4*)&Ws[wk * 136 + wn + 8] = w1.v;
        __syncthreads();
#pragma unroll 4
        for (int k = 0; k < 32; ++k) {
            uint4 ap = *(const uint4*)&As[k * 136 + ty * 8];
            uint4 bp = *(const uint4*)&Ws[k * 136 + tx * 8];
            float a[8], b[8];
            unpack8(ap, a);
            unpack8(bp, b);
#pragma unroll
            for (int i = 0; i < 8; ++i)
#pragma unroll
                for (int j = 0; j < 8; ++j)
                    acc[i][j] += a[i] * b[j];
        }
    }

    const int colbase = n0 + tx * 8;
    float bv[8];
#pragma unroll
    for (int j = 0; j < 8; ++j) bv[j] = lds1(bias, colbase + j, f32);

    void* dst; int sd; int cb;
    if (colbase < ncut) { dst = dst0; sd = sd0; cb = colbase; }
    else                { dst = dst1; sd = sd1; cb = colbase - ncut; }

#pragma unroll
    for (int i = 0; i < 8; ++i) {
        size_t off = (size_t)(m0 + ty * 8 + i) * sd + cb;
        if (MATCH_OUT && f32) {
            float* dp = (float*)dst + off;
            *(float4*)dp       = make_float4(acc[i][0]+bv[0], acc[i][1]+bv[1], acc[i][2]+bv[2], acc[i][3]+bv[3]);
            *(float4*)(dp + 4) = make_float4(acc[i][4]+bv[4], acc[i][5]+bv[5], acc[i][6]+bv[6], acc[i][7]+bv[7]);
        } else {
            U8 o;
#pragma unroll
            for (int j = 0; j < 8; ++j) o.s[j] = f2bf(acc[i][j] + bv[j]);
            *(uint4*)((unsigned short*)dst + off) = o.v;
        }
    }
}

// Fused attention with interference + online softmax.
// qk: [2048][5120] bf16 (internal), Q cols [0,2560), K cols [2560,5120).
// vsrc: [2048][2560] bf16 (internal, parked in d_out).
// O overwrites the Q section in place (exclusive per-block region).
__global__ __launch_bounds__(256, 2) void attn_kernel(
    unsigned short* __restrict__ qk,
    const unsigned short* __restrict__ vsrc,
    const void* __restrict__ gmats,
    const void* __restrict__ gphases,
    const void* __restrict__ gamps,
    const void* __restrict__ qphase,
    const void* __restrict__ is_ptr,
    const int* __restrict__ flag)
{
    __shared__ float Qs[64 * 84];   // [qi][d] stride 84
    __shared__ float KV[80 * 68];   // K: [d][kj] stride 68; then V: [kj][d] stride 80
    __shared__ float Ss[64 * 68];   // scores/probs, stride 68
    __shared__ float cs[240];       // coeffs [3][80]

    const bool f32 = (*flag != 0);

    const int t  = threadIdx.x;
    const int qt = blockIdx.x & 15;
    const int bh = blockIdx.x >> 4;
    const int h  = bh & 31;
    const int b  = bh >> 5;

    const float scale = 0.111803398874989485f;   // 1/sqrt(80)
    const float isv   = lds1(is_ptr, 0, f32);
    const float c2    = scale * scale * isv * (1.0f / 3.0f);
    const float cosph = cosf(lds1(qphase, h, f32));

    if (t < 240) {
        int g = t / 80;
        float r0 = lds1(gmats, g*4+0, f32) + lds1(gmats, g*4+1, f32);
        float r1 = lds1(gmats, g*4+2, f32) + lds1(gmats, g*4+3, f32);
        float ph = lds1(gphases, t, f32);
        float am = lds1(gamps, t, f32);
        cs[t] = (cosf(ph) * r0 + sinf(ph) * r1) * am;
    }

    const int rr = t >> 2;   // 0..63
    const int dg = t & 3;    // quarter of D
    const int tx = t & 15;   // phase1 k dir
    const int ty = t >> 4;   // phase1 q dir

    {   // stage Q tile (persists across k-tiles)
        const unsigned short* qp = qk + (size_t)(b * S_ + qt * 64 + rr) * QK_ + h * D_ + dg * 20;
#pragma unroll
        for (int u = 0; u < 5; ++u)
            *(float4*)&Qs[rr * 84 + dg * 20 + 4 * u] = ld_bf4(qp + 4 * u);
    }

    float m_r = -INFINITY, l_r = 0.f;
    float4 Ov[5];
#pragma unroll
    for (int u = 0; u < 5; ++u) Ov[u] = make_float4(0.f, 0.f, 0.f, 0.f);

    for (int kt = 0; kt < 16; ++kt) {
        // ---- stage K (transposed [d][kj]) ----
        const unsigned short* kp = qk + (size_t)(b * S_ + kt * 64 + rr) * QK_ + E_ + h * D_ + dg * 20;
        float4 kf[5];
#pragma unroll
        for (int u = 0; u < 5; ++u) kf[u] = ld_bf4(kp + 4 * u);
        __syncthreads();   // prev iter's KV/Ss reads complete
#pragma unroll
        for (int u = 0; u < 5; ++u) {
            int d = dg * 20 + 4 * u;
            KV[(d+0)*68 + rr] = kf[u].x;
            KV[(d+1)*68 + rr] = kf[u].y;
            KV[(d+2)*68 + rr] = kf[u].z;
            KV[(d+3)*68 + rr] = kf[u].w;
        }
        __syncthreads();   // KV(K), Qs, cs visible

        // ---- phase 1: 4-way scores, 4x4 per thread ----
        float sb[4][4], s0[4][4], s1[4][4], s2[4][4];
#pragma unroll
        for (int i = 0; i < 4; ++i)
#pragma unroll
            for (int j = 0; j < 4; ++j) { sb[i][j]=0.f; s0[i][j]=0.f; s1[i][j]=0.f; s2[i][j]=0.f; }

#pragma unroll 2
        for (int dd = 0; dd < 80; dd += 4) {
            float aA[4][4];
#pragma unroll
            for (int i = 0; i < 4; ++i) {
                float4 v = *(const float4*)&Qs[(ty*4+i)*84 + dd];
                aA[i][0]=v.x; aA[i][1]=v.y; aA[i][2]=v.z; aA[i][3]=v.w;
            }
            float bB[4][4];
#pragma unroll
            for (int u = 0; u < 4; ++u) {
                float4 v = *(const float4*)&KV[(dd+u)*68 + tx*4];
                bB[u][0]=v.x; bB[u][1]=v.y; bB[u][2]=v.z; bB[u][3]=v.w;
            }
            float4 c0v = *(const float4*)&cs[0*80 + dd];
            float4 c1v = *(const float4*)&cs[1*80 + dd];
            float4 c2v = *(const float4*)&cs[2*80 + dd];
            float cA[3][4];
            cA[0][0]=c0v.x; cA[0][1]=c0v.y; cA[0][2]=c0v.z; cA[0][3]=c0v.w;
            cA[1][0]=c1v.x; cA[1][1]=c1v.y; cA[1][2]=c1v.z; cA[1][3]=c1v.w;
            cA[2][0]=c2v.x; cA[2][1]=c2v.y; cA[2][2]=c2v.z; cA[2][3]=c2v.w;
#pragma unroll
            for (int u = 0; u < 4; ++u)
#pragma unroll
                for (int i = 0; i < 4; ++i)
#pragma unroll
                    for (int j = 0; j < 4; ++j) {
                        float p = aA[i][u] * bB[u][j];
                        sb[i][j] += p;
                        s0[i][j] += p * cA[0][u];
                        s1[i][j] += p * cA[1][u];
                        s2[i][j] += p * cA[2][u];
                    }
        }
#pragma unroll
        for (int i = 0; i < 4; ++i) {
            float4 o;
            o.x = sb[i][0]*scale + (s0[i][0]*s1[i][0] + s0[i][0]*s2[i][0] + s1[i][0]*s2[i][0]) * c2;
            o.y = sb[i][1]*scale + (s0[i][1]*s1[i][1] + s0[i][1]*s2[i][1] + s1[i][1]*s2[i][1]) * c2;
            o.z = sb[i][2]*scale + (s0[i][2]*s1[i][2] + s0[i][2]*s2[i][2] + s1[i][2]*s2[i][2]) * c2;
            o.w = sb[i][3]*scale + (s0[i][3]*s1[i][3] + s0[i][3]*s2[i][3] + s1[i][3]*s2[i][3]) * c2;
            *(float4*)&Ss[(ty*4+i)*68 + tx*4] = o;
        }
        __syncthreads();   // Ss complete; K reads complete (KV free for V)

        // ---- stage V into KV ([kj][d] stride 80) ----
        const unsigned short* vp = vsrc + (size_t)(b * S_ + kt * 64 + rr) * E_ + h * D_ + dg * 20;
#pragma unroll
        for (int u = 0; u < 5; ++u)
            *(float4*)&KV[rr * 80 + dg * 20 + 4 * u] = ld_bf4(vp + 4 * u);

        // ---- phase 2: online softmax (4 threads per row, own 16 cols each) ----
        float sv[16];
        float mx = -INFINITY;
        const int sbase = rr * 68 + dg * 16;
#pragma unroll
        for (int g = 0; g < 16; ++g) { sv[g] = Ss[sbase + g]; mx = fmaxf(mx, sv[g]); }
        mx = fmaxf(mx, __shfl_xor(mx, 1));
        mx = fmaxf(mx, __shfl_xor(mx, 2));
        float m_new = fmaxf(m_r, mx);
        float ssum = 0.f;
#pragma unroll
        for (int g = 0; g < 16; ++g) {
            float p = __expf(sv[g] - m_new);
            Ss[sbase + g] = p;
            ssum += p;
        }
        ssum += __shfl_xor(ssum, 1);
        ssum += __shfl_xor(ssum, 2);
        float alpha = __expf(m_r - m_new);
        l_r = l_r * alpha + ssum;
        m_r = m_new;
        __syncthreads();   // V + probs visible

        // ---- phase 3: O accumulate ----
#pragma unroll
        for (int u = 0; u < 5; ++u) {
            Ov[u].x *= alpha; Ov[u].y *= alpha; Ov[u].z *= alpha; Ov[u].w *= alpha;
        }
#pragma unroll 4
        for (int kj = 0; kj < 64; ++kj) {
            float p = Ss[rr * 68 + kj];
#pragma unroll
            for (int u = 0; u < 5; ++u) {
                float4 v = *(const float4*)&KV[kj * 80 + dg * 20 + 4 * u];
                Ov[u].x += p * v.x; Ov[u].y += p * v.y; Ov[u].z += p * v.z; Ov[u].w += p * v.w;
            }
        }
    }

    // epilogue: apply cos(phase)/l, overwrite Q section in place (bf16 internal)
    float inv_l = cosph / l_r;
    unsigned short* op = qk + (size_t)(b * S_ + qt * 64 + rr) * QK_ + h * D_ + dg * 20;
#pragma unroll
    for (int u = 0; u < 5; ++u) {
        op[4*u+0] = f2bf(Ov[u].x * inv_l);
        op[4*u+1] = f2bf(Ov[u].y * inv_l);
        op[4*u+2] = f2bf(Ov[u].z * inv_l);
        op[4*u+3] = f2bf(Ov[u].w * inv_l);
    }
}

extern "C" void kernel_launch(void* const* d_in, const int* in_sizes, int n_in,
                              void* d_out, int out_size, void* d_ws, size_t ws_size,
                              hipStream_t stream) {
    (void)in_sizes; (void)n_in; (void)out_size; (void)ws_size;
    const void* hidden  = d_in[0];
    const void* Wqkv    = d_in[1];
    const void* bqkv    = d_in[2];
    const void* Wproj   = d_in[3];
    const void* bproj   = d_in[4];
    const void* gmats   = d_in[5];
    const void* gphases = d_in[6];
    const void* gamps   = d_in[7];
    const void* qphase  = d_in[8];
    const void* is_ptr  = d_in[9];

    int* flag = (int*)d_ws;                                         // 256B header
    unsigned short* qk_ws = (unsigned short*)((char*)d_ws + 256);   // [2048][5120] bf16 = 20.97 MB
    unsigned short* v_buf = (unsigned short*)d_out;                 // V parked in d_out, consumed before proj

    dim3 blk(256);
    detect_kernel<<<1, 256, 0, stream>>>((const unsigned short*)Wqkv, flag);
    // QKV GEMM: (2048,2560)@(2560,7680); Q|K cols -> ws (bf16), V cols -> d_out (bf16)
    gemm_bias_kernel<false, false><<<dim3(E3_/128, M_/128), blk, 0, stream>>>(
        hidden, E_, Wqkv, E3_, E_, bqkv,
        qk_ws, QK_, v_buf, E_, QK_, flag);
    // fused attention (O overwrites Q section of ws)
    attn_kernel<<<dim3(2 * H_ * (S_/64)), blk, 0, stream>>>(
        qk_ws, v_buf, gmats, gphases, gamps, qphase, is_ptr, flag);
    // proj GEMM: A is INTERNAL bf16 (qk_ws) — never read per flag; W/bias/out per flag
    gemm_bias_kernel<true, true><<<dim3(E_/128, M_/128), blk, 0, stream>>>(
        qk_ws, QK_, Wproj, E_, E_, bproj,
        d_out, E_, d_out, E_, E_, flag);
}

// Round 5
// 1252.992 us; speedup vs baseline: 2.1994x; 2.1994x over previous
//
#include <hip/hip_runtime.h>
#include <hip/hip_bf16.h>
#include <math.h>

#define S_  1024
#define E_  2560
#define H_  32
#define D_  80
#define E3_ 7680
#define M_  2048   // B*S
#define QK_ 5120   // packed Q|K row width in ws

typedef short bf16x8 __attribute__((ext_vector_type(8)));
typedef float f32x4  __attribute__((ext_vector_type(4)));

static __device__ __forceinline__ float bf2f(unsigned short u) {
    unsigned int i = ((unsigned int)u) << 16;
    float f; __builtin_memcpy(&f, &i, 4); return f;
}
static __device__ __forceinline__ unsigned short f2bf(float f) {
    unsigned int i; __builtin_memcpy(&i, &f, 4);
    i += 0x7fffu + ((i >> 16) & 1u);
    return (unsigned short)(i >> 16);
}
static __device__ __forceinline__ float4 ld_bf4(const unsigned short* p) {
    ushort4 u = *(const ushort4*)p;   // 8B-aligned
    return make_float4(bf2f(u.x), bf2f(u.y), bf2f(u.z), bf2f(u.w));
}

// ---------- pre-pass: fp32 -> bf16 flat convert ----------
__global__ __launch_bounds__(256) void cvt_bf16_kernel(
    const float* __restrict__ in, unsigned short* __restrict__ out, int n8)
{
    int i = (blockIdx.x * 256 + threadIdx.x);
    if (i >= n8) return;
    const float* p = in + (size_t)i * 8;
    float4 a = *(const float4*)p;
    float4 b = *(const float4*)(p + 4);
    union { uint4 v; unsigned short s[8]; } o;
    o.s[0]=f2bf(a.x); o.s[1]=f2bf(a.y); o.s[2]=f2bf(a.z); o.s[3]=f2bf(a.w);
    o.s[4]=f2bf(b.x); o.s[5]=f2bf(b.y); o.s[6]=f2bf(b.z); o.s[7]=f2bf(b.w);
    *(uint4*)(out + (size_t)i * 8) = o.v;
}

// ---------- pre-pass: fp32 [R][C] -> bf16 [C][R] transpose-convert ----------
// 64x64 tile per block, 4x4 per thread, in-register transpose.
__global__ __launch_bounds__(256) void transpose_bf16_kernel(
    const float* __restrict__ in, unsigned short* __restrict__ out, int R, int C)
{
    const int t = threadIdx.x;
    const int r0 = blockIdx.y * 64, c0 = blockIdx.x * 64;
    const int r4 = (t >> 4) * 4;       // 0..60
    const int c4 = (t & 15) * 4;       // 0..60
    float4 rows[4];
#pragma unroll
    for (int i = 0; i < 4; ++i)
        rows[i] = *(const float4*)&in[(size_t)(r0 + r4 + i) * C + c0 + c4];
    const float rv[4][4] = {
        {rows[0].x, rows[0].y, rows[0].z, rows[0].w},
        {rows[1].x, rows[1].y, rows[1].z, rows[1].w},
        {rows[2].x, rows[2].y, rows[2].z, rows[2].w},
        {rows[3].x, rows[3].y, rows[3].z, rows[3].w}};
#pragma unroll
    for (int j = 0; j < 4; ++j) {
        ushort4 o;
        o.x = f2bf(rv[0][j]); o.y = f2bf(rv[1][j]);
        o.z = f2bf(rv[2][j]); o.w = f2bf(rv[3][j]);
        *(ushort4*)&out[(size_t)(c0 + c4 + j) * R + r0 + r4] = o;
    }
}

// ---------- MFMA GEMM ----------
// C[M,N] = A[M,K] @ Wt[N,K]^T + bias;  A: fp32 (A_F32) or bf16; Wt bf16 [N][K].
// 128x128 tile, BK=32, 4 waves, each wave 64x64 (4x4 frags of 16x16x32).
// Output: cols [0,ncut) -> dst0 (stride sd0, bf16), cols >= ncut -> dst1 (stride sd1, bf16);
// OUT_F32: single fp32 dest (dst0).
template <bool A_F32, bool OUT_F32>
__global__ __launch_bounds__(256, 2) void mfma_gemm_kernel(
    const void* __restrict__ A, int lda,
    const unsigned short* __restrict__ Wt,
    const float* __restrict__ bias,
    void* __restrict__ dst0, int sd0,
    void* __restrict__ dst1, int sd1, int ncut,
    int K)
{
    __shared__ unsigned short As[128 * 40];  // [m][k] pad 40 (80B rows, 16B aligned)
    __shared__ unsigned short Bs[128 * 40];  // [n][k]

    const int t    = threadIdx.x;
    const int m0   = blockIdx.y * 128;
    const int n0   = blockIdx.x * 128;
    const int lane = t & 63, wave = t >> 6;
    const int quad = lane >> 4, l15 = lane & 15;
    const int mw   = (wave >> 1) * 64;
    const int nw   = (wave & 1) * 64;
    const int r    = t >> 1;            // staging row 0..127
    const int hh   = (t & 1) * 16;      // staging k-half

    f32x4 acc[4][4];
#pragma unroll
    for (int i = 0; i < 4; ++i)
#pragma unroll
        for (int j = 0; j < 4; ++j) acc[i][j] = (f32x4){0.f, 0.f, 0.f, 0.f};

    const size_t a_base = (size_t)(m0 + r) * lda + hh;
    const unsigned short* bp = Wt + (size_t)(n0 + r) * K + hh;

    for (int k0 = 0; k0 < K; k0 += 32) {
        uint4 a0, a1;
        if (A_F32) {
            const float* ap = (const float*)A + a_base + k0;
            float4 f0 = *(const float4*)ap;
            float4 f1 = *(const float4*)(ap + 4);
            float4 f2 = *(const float4*)(ap + 8);
            float4 f3 = *(const float4*)(ap + 12);
            union { uint4 v; unsigned short s[8]; } u0, u1;
            u0.s[0]=f2bf(f0.x); u0.s[1]=f2bf(f0.y); u0.s[2]=f2bf(f0.z); u0.s[3]=f2bf(f0.w);
            u0.s[4]=f2bf(f1.x); u0.s[5]=f2bf(f1.y); u0.s[6]=f2bf(f1.z); u0.s[7]=f2bf(f1.w);
            u1.s[0]=f2bf(f2.x); u1.s[1]=f2bf(f2.y); u1.s[2]=f2bf(f2.z); u1.s[3]=f2bf(f2.w);
            u1.s[4]=f2bf(f3.x); u1.s[5]=f2bf(f3.y); u1.s[6]=f2bf(f3.z); u1.s[7]=f2bf(f3.w);
            a0 = u0.v; a1 = u1.v;
        } else {
            const unsigned short* ap = (const unsigned short*)A + a_base + k0;
            a0 = *(const uint4*)ap;
            a1 = *(const uint4*)(ap + 8);
        }
        uint4 b0 = *(const uint4*)(bp + k0);
        uint4 b1 = *(const uint4*)(bp + k0 + 8);
        __syncthreads();  // prev iter's frag reads complete
        *(uint4*)&As[r * 40 + hh]     = a0;
        *(uint4*)&As[r * 40 + hh + 8] = a1;
        *(uint4*)&Bs[r * 40 + hh]     = b0;
        *(uint4*)&Bs[r * 40 + hh + 8] = b1;
        __syncthreads();

        bf16x8 af[4], bfr[4];
#pragma unroll
        for (int i = 0; i < 4; ++i)
            af[i] = *(const bf16x8*)&As[(mw + i * 16 + l15) * 40 + quad * 8];
#pragma unroll
        for (int j = 0; j < 4; ++j)
            bfr[j] = *(const bf16x8*)&Bs[(nw + j * 16 + l15) * 40 + quad * 8];
#pragma unroll
        for (int i = 0; i < 4; ++i)
#pragma unroll
            for (int j = 0; j < 4; ++j)
                acc[i][j] = __builtin_amdgcn_mfma_f32_16x16x32_bf16(af[i], bfr[j], acc[i][j], 0, 0, 0);
    }

    // epilogue: C/D layout col=lane&15, row=quad*4+reg  [m89/m91 verified]
#pragma unroll
    for (int j = 0; j < 4; ++j) {
        const int col = n0 + nw + j * 16 + l15;
        const float bv = bias[col];
        if (OUT_F32) {
            float* dst = (float*)dst0;
#pragma unroll
            for (int i = 0; i < 4; ++i) {
                const int rowb = m0 + mw + i * 16 + quad * 4;
#pragma unroll
                for (int g = 0; g < 4; ++g)
                    dst[(size_t)(rowb + g) * sd0 + col] = acc[i][j][g] + bv;
            }
        } else {
            unsigned short* dst; int sd, cc;
            if (col < ncut) { dst = (unsigned short*)dst0; sd = sd0; cc = col; }
            else            { dst = (unsigned short*)dst1; sd = sd1; cc = col - ncut; }
#pragma unroll
            for (int i = 0; i < 4; ++i) {
                const int rowb = m0 + mw + i * 16 + quad * 4;
#pragma unroll
                for (int g = 0; g < 4; ++g)
                    dst[(size_t)(rowb + g) * sd + cc] = f2bf(acc[i][j][g] + bv);
            }
        }
    }
}

// ---------- fused attention (unchanged math from round 4, fp32 params) ----------
__global__ __launch_bounds__(256, 2) void attn_kernel(
    unsigned short* __restrict__ qk,        // [2048][5120] bf16: Q cols [0,2560), K [2560,5120)
    const unsigned short* __restrict__ vsrc,// [2048][2560] bf16 (parked in d_out)
    const float* __restrict__ gmats,
    const float* __restrict__ gphases,
    const float* __restrict__ gamps,
    const float* __restrict__ qphase,
    const float* __restrict__ is_ptr)
{
    __shared__ float Qs[64 * 84];
    __shared__ float KV[80 * 68];   // K: [d][kj] s68; then V: [kj][d] s80
    __shared__ float Ss[64 * 68];
    __shared__ float cs[240];

    const int t  = threadIdx.x;
    const int qt = blockIdx.x & 15;
    const int bh = blockIdx.x >> 4;
    const int h  = bh & 31;
    const int b  = bh >> 5;

    const float scale = 0.111803398874989485f;
    const float c2    = scale * scale * is_ptr[0] * (1.0f / 3.0f);
    const float cosph = cosf(qphase[h]);

    if (t < 240) {
        int g = t / 80;
        float r0 = gmats[g*4+0] + gmats[g*4+1];
        float r1 = gmats[g*4+2] + gmats[g*4+3];
        cs[t] = (cosf(gphases[t]) * r0 + sinf(gphases[t]) * r1) * gamps[t];
    }

    const int rr = t >> 2;
    const int dg = t & 3;
    const int tx = t & 15;
    const int ty = t >> 4;

    {
        const unsigned short* qp = qk + (size_t)(b * S_ + qt * 64 + rr) * QK_ + h * D_ + dg * 20;
#pragma unroll
        for (int u = 0; u < 5; ++u)
            *(float4*)&Qs[rr * 84 + dg * 20 + 4 * u] = ld_bf4(qp + 4 * u);
    }

    float m_r = -INFINITY, l_r = 0.f;
    float4 Ov[5];
#pragma unroll
    for (int u = 0; u < 5; ++u) Ov[u] = make_float4(0.f, 0.f, 0.f, 0.f);

    for (int kt = 0; kt < 16; ++kt) {
        const unsigned short* kp = qk + (size_t)(b * S_ + kt * 64 + rr) * QK_ + E_ + h * D_ + dg * 20;
        float4 kf[5];
#pragma unroll
        for (int u = 0; u < 5; ++u) kf[u] = ld_bf4(kp + 4 * u);
        __syncthreads();
#pragma unroll
        for (int u = 0; u < 5; ++u) {
            int d = dg * 20 + 4 * u;
            KV[(d+0)*68 + rr] = kf[u].x;
            KV[(d+1)*68 + rr] = kf[u].y;
            KV[(d+2)*68 + rr] = kf[u].z;
            KV[(d+3)*68 + rr] = kf[u].w;
        }
        __syncthreads();

        float sb[4][4], s0[4][4], s1[4][4], s2[4][4];
#pragma unroll
        for (int i = 0; i < 4; ++i)
#pragma unroll
            for (int j = 0; j < 4; ++j) { sb[i][j]=0.f; s0[i][j]=0.f; s1[i][j]=0.f; s2[i][j]=0.f; }

#pragma unroll 2
        for (int dd = 0; dd < 80; dd += 4) {
            float aA[4][4];
#pragma unroll
            for (int i = 0; i < 4; ++i) {
                float4 v = *(const float4*)&Qs[(ty*4+i)*84 + dd];
                aA[i][0]=v.x; aA[i][1]=v.y; aA[i][2]=v.z; aA[i][3]=v.w;
            }
            float bB[4][4];
#pragma unroll
            for (int u = 0; u < 4; ++u) {
                float4 v = *(const float4*)&KV[(dd+u)*68 + tx*4];
                bB[u][0]=v.x; bB[u][1]=v.y; bB[u][2]=v.z; bB[u][3]=v.w;
            }
            float4 c0v = *(const float4*)&cs[0*80 + dd];
            float4 c1v = *(const float4*)&cs[1*80 + dd];
            float4 c2v = *(const float4*)&cs[2*80 + dd];
            float cA[3][4];
            cA[0][0]=c0v.x; cA[0][1]=c0v.y; cA[0][2]=c0v.z; cA[0][3]=c0v.w;
            cA[1][0]=c1v.x; cA[1][1]=c1v.y; cA[1][2]=c1v.z; cA[1][3]=c1v.w;
            cA[2][0]=c2v.x; cA[2][1]=c2v.y; cA[2][2]=c2v.z; cA[2][3]=c2v.w;
#pragma unroll
            for (int u = 0; u < 4; ++u)
#pragma unroll
                for (int i = 0; i < 4; ++i)
#pragma unroll
                    for (int j = 0; j < 4; ++j) {
                        float p = aA[i][u] * bB[u][j];
                        sb[i][j] += p;
                        s0[i][j] += p * cA[0][u];
                        s1[i][j] += p * cA[1][u];
                        s2[i][j] += p * cA[2][u];
                    }
        }
#pragma unroll
        for (int i = 0; i < 4; ++i) {
            float4 o;
            o.x = sb[i][0]*scale + (s0[i][0]*s1[i][0] + s0[i][0]*s2[i][0] + s1[i][0]*s2[i][0]) * c2;
            o.y = sb[i][1]*scale + (s0[i][1]*s1[i][1] + s0[i][1]*s2[i][1] + s1[i][1]*s2[i][1]) * c2;
            o.z = sb[i][2]*scale + (s0[i][2]*s1[i][2] + s0[i][2]*s2[i][2] + s1[i][2]*s2[i][2]) * c2;
            o.w = sb[i][3]*scale + (s0[i][3]*s1[i][3] + s0[i][3]*s2[i][3] + s1[i][3]*s2[i][3]) * c2;
            *(float4*)&Ss[(ty*4+i)*68 + tx*4] = o;
        }
        __syncthreads();

        const unsigned short* vp = vsrc + (size_t)(b * S_ + kt * 64 + rr) * E_ + h * D_ + dg * 20;
#pragma unroll
        for (int u = 0; u < 5; ++u)
            *(float4*)&KV[rr * 80 + dg * 20 + 4 * u] = ld_bf4(vp + 4 * u);

        float sv[16];
        float mx = -INFINITY;
        const int sbase = rr * 68 + dg * 16;
#pragma unroll
        for (int g = 0; g < 16; ++g) { sv[g] = Ss[sbase + g]; mx = fmaxf(mx, sv[g]); }
        mx = fmaxf(mx, __shfl_xor(mx, 1));
        mx = fmaxf(mx, __shfl_xor(mx, 2));
        float m_new = fmaxf(m_r, mx);
        float ssum = 0.f;
#pragma unroll
        for (int g = 0; g < 16; ++g) {
            float p = __expf(sv[g] - m_new);
            Ss[sbase + g] = p;
            ssum += p;
        }
        ssum += __shfl_xor(ssum, 1);
        ssum += __shfl_xor(ssum, 2);
        float alpha = __expf(m_r - m_new);
        l_r = l_r * alpha + ssum;
        m_r = m_new;
        __syncthreads();

#pragma unroll
        for (int u = 0; u < 5; ++u) {
            Ov[u].x *= alpha; Ov[u].y *= alpha; Ov[u].z *= alpha; Ov[u].w *= alpha;
        }
#pragma unroll 4
        for (int kj = 0; kj < 64; ++kj) {
            float p = Ss[rr * 68 + kj];
#pragma unroll
            for (int u = 0; u < 5; ++u) {
                float4 v = *(const float4*)&KV[kj * 80 + dg * 20 + 4 * u];
                Ov[u].x += p * v.x; Ov[u].y += p * v.y; Ov[u].z += p * v.z; Ov[u].w += p * v.w;
            }
        }
    }

    float inv_l = cosph / l_r;
    unsigned short* op = qk + (size_t)(b * S_ + qt * 64 + rr) * QK_ + h * D_ + dg * 20;
#pragma unroll
    for (int u = 0; u < 5; ++u) {
        op[4*u+0] = f2bf(Ov[u].x * inv_l);
        op[4*u+1] = f2bf(Ov[u].y * inv_l);
        op[4*u+2] = f2bf(Ov[u].z * inv_l);
        op[4*u+3] = f2bf(Ov[u].w * inv_l);
    }
}

extern "C" void kernel_launch(void* const* d_in, const int* in_sizes, int n_in,
                              void* d_out, int out_size, void* d_ws, size_t ws_size,
                              hipStream_t stream) {
    (void)in_sizes; (void)n_in; (void)out_size; (void)ws_size;
    const float* hidden  = (const float*)d_in[0];
    const float* Wqkv    = (const float*)d_in[1];
    const float* bqkv    = (const float*)d_in[2];
    const float* Wproj   = (const float*)d_in[3];
    const float* bproj   = (const float*)d_in[4];
    const float* gmats   = (const float*)d_in[5];
    const float* gphases = (const float*)d_in[6];
    const float* gamps   = (const float*)d_in[7];
    const float* qphase  = (const float*)d_in[8];
    const float* is_ptr  = (const float*)d_in[9];

    // ws layout (70.8 MB): qk_ws 21.0 MB | h_bf16 10.5 MB | Wt 39.3 MB (reused for Wproj_t)
    unsigned short* qk_ws  = (unsigned short*)d_ws;
    unsigned short* h_bf16 = (unsigned short*)((char*)d_ws + (size_t)M_ * QK_ * 2);
    unsigned short* Wt     = (unsigned short*)((char*)d_ws + (size_t)M_ * QK_ * 2 + (size_t)M_ * E_ * 2);
    unsigned short* v_buf  = (unsigned short*)d_out;   // V bf16 parked in d_out (consumed by attn)

    dim3 blk(256);
    // 1) hidden fp32 -> bf16
    cvt_bf16_kernel<<<dim3((M_ * E_ / 8 + 255) / 256), blk, 0, stream>>>(hidden, h_bf16, M_ * E_ / 8);
    // 2) Wqkv [2560][7680] fp32 -> Wt [7680][2560] bf16
    transpose_bf16_kernel<<<dim3(E3_/64, E_/64), blk, 0, stream>>>(Wqkv, Wt, E_, E3_);
    // 3) QKV GEMM (MFMA): Q|K -> qk_ws (bf16), V -> d_out (bf16)
    mfma_gemm_kernel<false, false><<<dim3(E3_/128, M_/128), blk, 0, stream>>>(
        h_bf16, E_, Wt, bqkv, qk_ws, QK_, v_buf, E_, QK_, E_);
    // 4) fused attention (O overwrites Q section of qk_ws, bf16)
    attn_kernel<<<dim3(2 * H_ * (S_/64)), blk, 0, stream>>>(
        qk_ws, v_buf, gmats, gphases, gamps, qphase, is_ptr);
    // 5) Wproj [2560][2560] fp32 -> Wt [2560][2560] bf16
    transpose_bf16_kernel<<<dim3(E_/64, E_/64), blk, 0, stream>>>(Wproj, Wt, E_, E_);
    // 6) proj GEMM (MFMA): A = O (bf16, qk_ws cols 0..2560, lda 5120) -> d_out fp32
    mfma_gemm_kernel<false, true><<<dim3(E_/128, M_/128), blk, 0, stream>>>(
        qk_ws, QK_, Wt, bproj, d_out, E_, d_out, E_, E_, E_);
}

// Round 6
// 489.155 us; speedup vs baseline: 5.6339x; 2.5615x over previous
//
#include <hip/hip_runtime.h>
#include <hip/hip_bf16.h>
#include <math.h>

#define S_  1024
#define E_  2560
#define H_  32
#define D_  80
#define E3_ 7680
#define M_  2048   // B*S
#define QK_ 5120   // packed Q|K row width in ws

typedef short bf16x8 __attribute__((ext_vector_type(8)));
typedef float f32x4  __attribute__((ext_vector_type(4)));

static __device__ __forceinline__ float bf2f(unsigned short u) {
    unsigned int i = ((unsigned int)u) << 16;
    float f; __builtin_memcpy(&f, &i, 4); return f;
}
static __device__ __forceinline__ unsigned short f2bf(float f) {
    unsigned int i; __builtin_memcpy(&i, &f, 4);
    i += 0x7fffu + ((i >> 16) & 1u);
    return (unsigned short)(i >> 16);
}

// ---------- pre-pass: fp32 -> bf16 flat convert ----------
__global__ __launch_bounds__(256) void cvt_bf16_kernel(
    const float* __restrict__ in, unsigned short* __restrict__ out, int n8)
{
    int i = (blockIdx.x * 256 + threadIdx.x);
    if (i >= n8) return;
    const float* p = in + (size_t)i * 8;
    float4 a = *(const float4*)p;
    float4 b = *(const float4*)(p + 4);
    union { uint4 v; unsigned short s[8]; } o;
    o.s[0]=f2bf(a.x); o.s[1]=f2bf(a.y); o.s[2]=f2bf(a.z); o.s[3]=f2bf(a.w);
    o.s[4]=f2bf(b.x); o.s[5]=f2bf(b.y); o.s[6]=f2bf(b.z); o.s[7]=f2bf(b.w);
    *(uint4*)(out + (size_t)i * 8) = o.v;
}

// ---------- pre-pass: fp32 [R][C] -> bf16 [C][R] transpose-convert ----------
__global__ __launch_bounds__(256) void transpose_bf16_kernel(
    const float* __restrict__ in, unsigned short* __restrict__ out, int R, int C)
{
    const int t = threadIdx.x;
    const int r0 = blockIdx.y * 64, c0 = blockIdx.x * 64;
    const int r4 = (t >> 4) * 4;
    const int c4 = (t & 15) * 4;
    float4 rows[4];
#pragma unroll
    for (int i = 0; i < 4; ++i)
        rows[i] = *(const float4*)&in[(size_t)(r0 + r4 + i) * C + c0 + c4];
    const float rv[4][4] = {
        {rows[0].x, rows[0].y, rows[0].z, rows[0].w},
        {rows[1].x, rows[1].y, rows[1].z, rows[1].w},
        {rows[2].x, rows[2].y, rows[2].z, rows[2].w},
        {rows[3].x, rows[3].y, rows[3].z, rows[3].w}};
#pragma unroll
    for (int j = 0; j < 4; ++j) {
        ushort4 o;
        o.x = f2bf(rv[0][j]); o.y = f2bf(rv[1][j]);
        o.z = f2bf(rv[2][j]); o.w = f2bf(rv[3][j]);
        *(ushort4*)&out[(size_t)(c0 + c4 + j) * R + r0 + r4] = o;
    }
}

// ---------- MFMA GEMM (round-5, unchanged) ----------
template <bool A_F32, bool OUT_F32>
__global__ __launch_bounds__(256, 2) void mfma_gemm_kernel(
    const void* __restrict__ A, int lda,
    const unsigned short* __restrict__ Wt,
    const float* __restrict__ bias,
    void* __restrict__ dst0, int sd0,
    void* __restrict__ dst1, int sd1, int ncut,
    int K)
{
    __shared__ unsigned short As[128 * 40];
    __shared__ unsigned short Bs[128 * 40];

    const int t    = threadIdx.x;
    const int m0   = blockIdx.y * 128;
    const int n0   = blockIdx.x * 128;
    const int lane = t & 63, wave = t >> 6;
    const int quad = lane >> 4, l15 = lane & 15;
    const int mw   = (wave >> 1) * 64;
    const int nw   = (wave & 1) * 64;
    const int r    = t >> 1;
    const int hh   = (t & 1) * 16;

    f32x4 acc[4][4];
#pragma unroll
    for (int i = 0; i < 4; ++i)
#pragma unroll
        for (int j = 0; j < 4; ++j) acc[i][j] = (f32x4){0.f, 0.f, 0.f, 0.f};

    const size_t a_base = (size_t)(m0 + r) * lda + hh;
    const unsigned short* bp = Wt + (size_t)(n0 + r) * K + hh;

    for (int k0 = 0; k0 < K; k0 += 32) {
        uint4 a0, a1;
        if (A_F32) {
            const float* ap = (const float*)A + a_base + k0;
            float4 f0 = *(const float4*)ap;
            float4 f1 = *(const float4*)(ap + 4);
            float4 f2 = *(const float4*)(ap + 8);
            float4 f3 = *(const float4*)(ap + 12);
            union { uint4 v; unsigned short s[8]; } u0, u1;
            u0.s[0]=f2bf(f0.x); u0.s[1]=f2bf(f0.y); u0.s[2]=f2bf(f0.z); u0.s[3]=f2bf(f0.w);
            u0.s[4]=f2bf(f1.x); u0.s[5]=f2bf(f1.y); u0.s[6]=f2bf(f1.z); u0.s[7]=f2bf(f1.w);
            u1.s[0]=f2bf(f2.x); u1.s[1]=f2bf(f2.y); u1.s[2]=f2bf(f2.z); u1.s[3]=f2bf(f2.w);
            u1.s[4]=f2bf(f3.x); u1.s[5]=f2bf(f3.y); u1.s[6]=f2bf(f3.z); u1.s[7]=f2bf(f3.w);
            a0 = u0.v; a1 = u1.v;
        } else {
            const unsigned short* ap = (const unsigned short*)A + a_base + k0;
            a0 = *(const uint4*)ap;
            a1 = *(const uint4*)(ap + 8);
        }
        uint4 b0 = *(const uint4*)(bp + k0);
        uint4 b1 = *(const uint4*)(bp + k0 + 8);
        __syncthreads();
        *(uint4*)&As[r * 40 + hh]     = a0;
        *(uint4*)&As[r * 40 + hh + 8] = a1;
        *(uint4*)&Bs[r * 40 + hh]     = b0;
        *(uint4*)&Bs[r * 40 + hh + 8] = b1;
        __syncthreads();

        bf16x8 af[4], bfr[4];
#pragma unroll
        for (int i = 0; i < 4; ++i)
            af[i] = *(const bf16x8*)&As[(mw + i * 16 + l15) * 40 + quad * 8];
#pragma unroll
        for (int j = 0; j < 4; ++j)
            bfr[j] = *(const bf16x8*)&Bs[(nw + j * 16 + l15) * 40 + quad * 8];
#pragma unroll
        for (int i = 0; i < 4; ++i)
#pragma unroll
            for (int j = 0; j < 4; ++j)
                acc[i][j] = __builtin_amdgcn_mfma_f32_16x16x32_bf16(af[i], bfr[j], acc[i][j], 0, 0, 0);
    }

#pragma unroll
    for (int j = 0; j < 4; ++j) {
        const int col = n0 + nw + j * 16 + l15;
        const float bv = bias[col];
        if (OUT_F32) {
            float* dst = (float*)dst0;
#pragma unroll
            for (int i = 0; i < 4; ++i) {
                const int rowb = m0 + mw + i * 16 + quad * 4;
#pragma unroll
                for (int g = 0; g < 4; ++g)
                    dst[(size_t)(rowb + g) * sd0 + col] = acc[i][j][g] + bv;
            }
        } else {
            unsigned short* dst; int sd, cc;
            if (col < ncut) { dst = (unsigned short*)dst0; sd = sd0; cc = col; }
            else            { dst = (unsigned short*)dst1; sd = sd1; cc = col - ncut; }
#pragma unroll
            for (int i = 0; i < 4; ++i) {
                const int rowb = m0 + mw + i * 16 + quad * 4;
#pragma unroll
                for (int g = 0; g < 4; ++g)
                    dst[(size_t)(rowb + g) * sd + cc] = f2bf(acc[i][j][g] + bv);
            }
        }
    }
}

// ---------- MFMA fused attention ----------
// Per block: (b, h, 64-row q-tile). 4 waves; wave w owns q-rows 16w..16w+15.
// Scores: A = Q-variant frags (registers, persist), B = K tile [kj][d] in LDS.
// PV:     A = P (LDS round-trip),                 B = V^T [d][kj] in LDS.
__global__ __launch_bounds__(256, 2) void attn_mfma_kernel(
    unsigned short* __restrict__ qk,         // [2048][5120] bf16: Q [0,2560), K [2560,5120)
    const unsigned short* __restrict__ vsrc, // [2048][2560] bf16 (parked in d_out)
    const float* __restrict__ gmats,
    const float* __restrict__ gphases,
    const float* __restrict__ gamps,
    const float* __restrict__ qphase,
    const float* __restrict__ is_ptr)
{
    __shared__ unsigned short Ks[64 * 104]; // Q tile (prologue) then K tiles; [row][d], pad d 80..96 = 0
    __shared__ unsigned short Vt[80 * 72];  // V^T [d][kj]
    __shared__ unsigned short Ps[64 * 72];  // P [q][kj] bf16
    __shared__ float cs[240];               // coeffs [3][80]

    const int t    = threadIdx.x;
    const int wave = t >> 6, lane = t & 63;
    const int quad = lane >> 4, l15 = lane & 15;
    const int qt = blockIdx.x & 15;
    const int bh = blockIdx.x >> 4;
    const int h  = bh & 31;
    const int b  = bh >> 5;

    const float scale = 0.111803398874989485f;   // 1/sqrt(80)
    const float c2    = scale * scale * is_ptr[0] * (1.0f / 3.0f);
    const float cosph = cosf(qphase[h]);

    if (t < 240) {
        int g = t / 80;
        float r0 = gmats[g*4+0] + gmats[g*4+1];
        float r1 = gmats[g*4+2] + gmats[g*4+3];
        cs[t] = (cosf(gphases[t]) * r0 + sinf(gphases[t]) * r1) * gamps[t];
    }

    const int srow = t >> 2;          // staging row 0..63 (wave w stages rows 16w..16w+15)
    const int scg  = (t & 3) * 20;    // staging col group (20 bf16)

    {   // stage Q tile into Ks + zero the d-pad [80,96)
        const unsigned short* qp = qk + (size_t)(b * S_ + qt * 64 + srow) * QK_ + h * D_ + scg;
#pragma unroll
        for (int u = 0; u < 5; ++u)
            *(ushort4*)&Ks[srow * 104 + scg + 4 * u] = *(const ushort4*)(qp + 4 * u);
        *(ushort4*)&Ks[srow * 104 + 80 + (t & 3) * 4] = (ushort4){0, 0, 0, 0};
    }
    __syncthreads();   // cs + Q visible

    // A-fragments: base Q + 3 coefficient-scaled variants (persist across k-tiles)
    bf16x8 afq[3], afg[3][3];
#pragma unroll
    for (int kc = 0; kc < 3; ++kc)
        afq[kc] = *(const bf16x8*)&Ks[(wave * 16 + l15) * 104 + quad * 8 + kc * 32];
#pragma unroll
    for (int g = 0; g < 3; ++g)
#pragma unroll
        for (int kc = 0; kc < 3; ++kc)
#pragma unroll
            for (int j = 0; j < 8; ++j) {
                int d = kc * 32 + quad * 8 + j;
                float c = (d < 80) ? cs[g * 80 + d] : 0.f;
                afg[g][kc][j] = (short)f2bf(bf2f((unsigned short)afq[kc][j]) * c);
            }

    f32x4 Ov[5];
#pragma unroll
    for (int nf = 0; nf < 5; ++nf) Ov[nf] = (f32x4){0.f, 0.f, 0.f, 0.f};
    float m_r[4] = {-INFINITY, -INFINITY, -INFINITY, -INFINITY};
    float l_r[4] = {0.f, 0.f, 0.f, 0.f};

    for (int kt = 0; kt < 16; ++kt) {
        __syncthreads();   // prev iter's Ks/Vt/Ps reads complete (iter0: Q-frag reads done)

        // ---- stage K tile [kj][d] into Ks (pad stays 0) ----
        const unsigned short* kp = qk + (size_t)(b * S_ + kt * 64 + srow) * QK_ + E_ + h * D_ + scg;
#pragma unroll
        for (int u = 0; u < 5; ++u)
            *(ushort4*)&Ks[srow * 104 + scg + 4 * u] = *(const ushort4*)(kp + 4 * u);

        // ---- stage V^T [d][kj] via 4x4 in-register transpose ----
        for (int s = t; s < 320; s += 256) {
            const int dg = s % 20, kg = s / 20;
            ushort4 rv[4];
#pragma unroll
            for (int i = 0; i < 4; ++i)
                rv[i] = *(const ushort4*)&vsrc[(size_t)(b * S_ + kt * 64 + kg * 4 + i) * E_ + h * D_ + dg * 4];
            const unsigned short rm[4][4] = {
                {rv[0].x, rv[0].y, rv[0].z, rv[0].w},
                {rv[1].x, rv[1].y, rv[1].z, rv[1].w},
                {rv[2].x, rv[2].y, rv[2].z, rv[2].w},
                {rv[3].x, rv[3].y, rv[3].z, rv[3].w}};
#pragma unroll
            for (int j = 0; j < 4; ++j) {
                ushort4 w = {rm[0][j], rm[1][j], rm[2][j], rm[3][j]};
                *(ushort4*)&Vt[(dg * 4 + j) * 72 + kg * 4] = w;
            }
        }
        __syncthreads();

        // ---- score MFMAs: 4 variants x 4 n-frags x 3 k-chunks ----
        f32x4 sacc[4][4];
#pragma unroll
        for (int v = 0; v < 4; ++v)
#pragma unroll
            for (int nf = 0; nf < 4; ++nf) sacc[v][nf] = (f32x4){0.f, 0.f, 0.f, 0.f};
#pragma unroll
        for (int kc = 0; kc < 3; ++kc) {
            bf16x8 bk[4];
#pragma unroll
            for (int nf = 0; nf < 4; ++nf)
                bk[nf] = *(const bf16x8*)&Ks[(nf * 16 + l15) * 104 + quad * 8 + kc * 32];
#pragma unroll
            for (int nf = 0; nf < 4; ++nf)
                sacc[0][nf] = __builtin_amdgcn_mfma_f32_16x16x32_bf16(afq[kc], bk[nf], sacc[0][nf], 0, 0, 0);
#pragma unroll
            for (int g = 0; g < 3; ++g)
#pragma unroll
                for (int nf = 0; nf < 4; ++nf)
                    sacc[1+g][nf] = __builtin_amdgcn_mfma_f32_16x16x32_bf16(afg[g][kc], bk[nf], sacc[1+g][nf], 0, 0, 0);
        }

        // ---- combine + online softmax (C layout: row=quad*4+r, col=l15+16nf) ----
        float p[4][4];   // [nf][r]
        float mx[4] = {-INFINITY, -INFINITY, -INFINITY, -INFINITY};
#pragma unroll
        for (int nf = 0; nf < 4; ++nf)
#pragma unroll
            for (int r = 0; r < 4; ++r) {
                float s0 = sacc[1][nf][r], s1 = sacc[2][nf][r], s2 = sacc[3][nf][r];
                float s = sacc[0][nf][r] * scale + (s0 * s1 + s0 * s2 + s1 * s2) * c2;
                p[nf][r] = s;
                mx[r] = fmaxf(mx[r], s);
            }
#pragma unroll
        for (int r = 0; r < 4; ++r) {
            mx[r] = fmaxf(mx[r], __shfl_xor(mx[r], 1));
            mx[r] = fmaxf(mx[r], __shfl_xor(mx[r], 2));
            mx[r] = fmaxf(mx[r], __shfl_xor(mx[r], 4));
            mx[r] = fmaxf(mx[r], __shfl_xor(mx[r], 8));
        }
        float alpha[4];
#pragma unroll
        for (int r = 0; r < 4; ++r) {
            float m_new = fmaxf(m_r[r], mx[r]);
            alpha[r] = __expf(m_r[r] - m_new);
            m_r[r] = m_new;
        }
#pragma unroll
        for (int nf = 0; nf < 4; ++nf)
#pragma unroll
            for (int r = 0; r < 4; ++r)
                p[nf][r] = __expf(p[nf][r] - m_r[r]);
#pragma unroll
        for (int r = 0; r < 4; ++r) {
            float s = p[0][r] + p[1][r] + p[2][r] + p[3][r];
            s += __shfl_xor(s, 1);
            s += __shfl_xor(s, 2);
            s += __shfl_xor(s, 4);
            s += __shfl_xor(s, 8);
            l_r[r] = l_r[r] * alpha[r] + s;
        }

        // ---- write P (bf16) to LDS; own-wave rows only ----
#pragma unroll
        for (int nf = 0; nf < 4; ++nf)
#pragma unroll
            for (int r = 0; r < 4; ++r)
                Ps[(wave * 16 + quad * 4 + r) * 72 + l15 + 16 * nf] = f2bf(p[nf][r]);
        __asm__ volatile("s_waitcnt lgkmcnt(0)" ::: "memory");

        // ---- O rescale + PV MFMAs ----
#pragma unroll
        for (int nf = 0; nf < 5; ++nf)
#pragma unroll
            for (int r = 0; r < 4; ++r) Ov[nf][r] *= alpha[r];

        bf16x8 ap[2];
#pragma unroll
        for (int kc = 0; kc < 2; ++kc)
            ap[kc] = *(const bf16x8*)&Ps[(wave * 16 + l15) * 72 + quad * 8 + kc * 32];
#pragma unroll
        for (int nf = 0; nf < 5; ++nf)
#pragma unroll
            for (int kc = 0; kc < 2; ++kc) {
                bf16x8 bv = *(const bf16x8*)&Vt[(nf * 16 + l15) * 72 + quad * 8 + kc * 32];
                Ov[nf] = __builtin_amdgcn_mfma_f32_16x16x32_bf16(ap[kc], bv, Ov[nf], 0, 0, 0);
            }
    }

    // ---- epilogue: O * cos(phase)/l -> Q section of qk (bf16) ----
    float inv[4];
#pragma unroll
    for (int r = 0; r < 4; ++r) inv[r] = cosph / l_r[r];
#pragma unroll
    for (int nf = 0; nf < 5; ++nf)
#pragma unroll
        for (int r = 0; r < 4; ++r)
            qk[(size_t)(b * S_ + qt * 64 + wave * 16 + quad * 4 + r) * QK_ + h * D_ + nf * 16 + l15]
                = f2bf(Ov[nf][r] * inv[r]);
}

extern "C" void kernel_launch(void* const* d_in, const int* in_sizes, int n_in,
                              void* d_out, int out_size, void* d_ws, size_t ws_size,
                              hipStream_t stream) {
    (void)in_sizes; (void)n_in; (void)out_size; (void)ws_size;
    const float* hidden  = (const float*)d_in[0];
    const float* Wqkv    = (const float*)d_in[1];
    const float* bqkv    = (const float*)d_in[2];
    const float* Wproj   = (const float*)d_in[3];
    const float* bproj   = (const float*)d_in[4];
    const float* gmats   = (const float*)d_in[5];
    const float* gphases = (const float*)d_in[6];
    const float* gamps   = (const float*)d_in[7];
    const float* qphase  = (const float*)d_in[8];
    const float* is_ptr  = (const float*)d_in[9];

    // ws layout (70.8 MB): qk_ws 21.0 MB | h_bf16 10.5 MB | Wt 39.3 MB (reused for Wproj_t)
    unsigned short* qk_ws  = (unsigned short*)d_ws;
    unsigned short* h_bf16 = (unsigned short*)((char*)d_ws + (size_t)M_ * QK_ * 2);
    unsigned short* Wt     = (unsigned short*)((char*)d_ws + (size_t)M_ * QK_ * 2 + (size_t)M_ * E_ * 2);
    unsigned short* v_buf  = (unsigned short*)d_out;   // V bf16 parked in d_out (consumed by attn)

    dim3 blk(256);
    cvt_bf16_kernel<<<dim3((M_ * E_ / 8 + 255) / 256), blk, 0, stream>>>(hidden, h_bf16, M_ * E_ / 8);
    transpose_bf16_kernel<<<dim3(E3_/64, E_/64), blk, 0, stream>>>(Wqkv, Wt, E_, E3_);
    mfma_gemm_kernel<false, false><<<dim3(E3_/128, M_/128), blk, 0, stream>>>(
        h_bf16, E_, Wt, bqkv, qk_ws, QK_, v_buf, E_, QK_, E_);
    attn_mfma_kernel<<<dim3(2 * H_ * (S_/64)), blk, 0, stream>>>(
        qk_ws, v_buf, gmats, gphases, gamps, qphase, is_ptr);
    transpose_bf16_kernel<<<dim3(E_/64, E_/64), blk, 0, stream>>>(Wproj, Wt, E_, E_);
    mfma_gemm_kernel<false, true><<<dim3(E_/128, M_/128), blk, 0, stream>>>(
        qk_ws, QK_, Wt, bproj, d_out, E_, d_out, E_, E_, E_);
}